// Round 16
// baseline (65.863 us; speedup 1.0000x reference)
//
#include <hip/hip_runtime.h>
#include <hip/hip_bf16.h>

#define BB 2
#define SS 4096
#define DD 512
#define HH 8
#define HDIM 64
#define WINW 128

typedef __attribute__((ext_vector_type(8))) __bf16 bf16x8;
typedef __attribute__((ext_vector_type(4))) float f32x4;
typedef unsigned short u16;

union Frag { bf16x8 v; uint4 u; };

__device__ __forceinline__ unsigned int f2bf(float f) {
    union { __hip_bfloat16 h; unsigned short u; } c;
    c.h = __float2bfloat16(f);
    return (unsigned int)c.u;
}

__device__ __forceinline__ void gload16(const void* g, void* l) {
    __builtin_amdgcn_global_load_lds(
        (const __attribute__((address_space(1))) unsigned int*)g,
        (__attribute__((address_space(3))) unsigned int*)l,
        16, 0, 0);
}

// ---------------- prep: X->bf16  +  W->bf16 transposed (merged) ----------------
__global__ __launch_bounds__(256) void prep(
    const float* __restrict__ X, u16* __restrict__ Xb,
    const float* __restrict__ Wq, const float* __restrict__ Wk,
    const float* __restrict__ Wv, const float* __restrict__ Wo,
    u16* __restrict__ Wt, u16* __restrict__ Wot)
{
    __shared__ float tile[64][65];
    if (blockIdx.x < 2048) {
        int t = blockIdx.x * 256 + threadIdx.x;
        const float4 a = *(const float4*)(X + (size_t)t * 8);
        const float4 b = *(const float4*)(X + (size_t)t * 8 + 4);
        union { u16 s[8]; uint4 u; } p;
        p.s[0] = (u16)f2bf(a.x); p.s[1] = (u16)f2bf(a.y);
        p.s[2] = (u16)f2bf(a.z); p.s[3] = (u16)f2bf(a.w);
        p.s[4] = (u16)f2bf(b.x); p.s[5] = (u16)f2bf(b.y);
        p.s[6] = (u16)f2bf(b.z); p.s[7] = (u16)f2bf(b.w);
        *(uint4*)(Xb + (size_t)t * 8) = p.u;
        return;
    }
    const int bid = blockIdx.x - 2048;          // 0..255
    const int which = bid >> 6;
    const int rem = bid & 63;
    const int k0 = (rem >> 3) * 64, n0 = (rem & 7) * 64;
    const float* W = (which == 0) ? Wq : (which == 1) ? Wk : (which == 2) ? Wv : Wo;
    const int tr = threadIdx.x >> 6, tc = threadIdx.x & 63;
    #pragma unroll
    for (int r = 0; r < 16; ++r)
        tile[tr * 16 + r][tc] = W[(size_t)(k0 + tr * 16 + r) * 512 + n0 + tc];
    __syncthreads();
    u16* dst = (which < 3) ? (Wt + (size_t)which * 512 * 512) : Wot;
    #pragma unroll
    for (int r = 0; r < 16; ++r) {
        int nrow = n0 + tr * 16 + r;
        dst[(size_t)nrow * 512 + k0 + tc] = (u16)f2bf(tile[tc][tr * 16 + r]);
    }
}

// ---------------- bf16 MFMA GEMM (known-good) ----------------
// MODE 0 epilogue folds 0.125*log2(e) into the K plane so attn's softmax can
// run in the exp2 domain with no per-score multiply.
template<int MODE>
__global__ __launch_bounds__(256) void gemm_bf16(
    const u16* __restrict__ A, const u16* __restrict__ Bt,
    const float* __restrict__ b0, const float* __restrict__ b1,
    const float* __restrict__ b2, void* __restrict__ outv)
{
    __shared__ char lds[16384];
    char* lA = lds;
    char* lB = lds + 8192;
    const int lane = threadIdx.x & 63;
    const int wave = threadIdx.x >> 6;
    const int wm = wave >> 1, wn = wave & 1;
    const int col = lane & 15, hi = lane >> 4;
    const int m0 = blockIdx.x * 128;
    const int n0 = blockIdx.y * 128;

    f32x4 acc[4][4];
    #pragma unroll
    for (int i = 0; i < 4; ++i)
        #pragma unroll
        for (int j = 0; j < 4; ++j) acc[i][j] = (f32x4){0.f, 0.f, 0.f, 0.f};

    char* la0 = lA + (wave * 32) * 64;
    char* la1 = la0 + 16 * 64;
    char* lb0 = lB + (wave * 32) * 64;
    char* lb1 = lb0 + 16 * 64;
    const int sg = (((lane & 3) ^ ((lane >> 2) & 3))) * 16;
    const char* gA = (const char*)(A + (size_t)(m0 + wave * 32 + (lane >> 2)) * 512) + sg;
    const char* gB = (const char*)(Bt + (size_t)(n0 + wave * 32 + (lane >> 2)) * 512) + sg;

    const int x4 = (col & 3);

    for (int kt = 0; kt < 16; ++kt) {
        gload16(gA + kt * 64, la0);
        gload16(gA + 16 * 1024 + kt * 64, la1);
        gload16(gB + kt * 64, lb0);
        gload16(gB + 16 * 1024 + kt * 64, lb1);
        __syncthreads();
        Frag af[4], bf[4];
        #pragma unroll
        for (int ms = 0; ms < 4; ++ms) {
            int R = wm * 64 + ms * 16 + col;
            af[ms].u = *(const uint4*)(lA + R * 64 + ((hi ^ x4) * 16));
        }
        #pragma unroll
        for (int ns = 0; ns < 4; ++ns) {
            int R = wn * 64 + ns * 16 + col;
            bf[ns].u = *(const uint4*)(lB + R * 64 + ((hi ^ x4) * 16));
        }
        __builtin_amdgcn_s_setprio(1);
        #pragma unroll
        for (int ms = 0; ms < 4; ++ms)
            #pragma unroll
            for (int ns = 0; ns < 4; ++ns)
                acc[ms][ns] = __builtin_amdgcn_mfma_f32_16x16x32_bf16(
                    af[ms].v, bf[ns].v, acc[ms][ns], 0, 0, 0);
        __builtin_amdgcn_s_setprio(0);
        __syncthreads();
    }

    if (MODE == 0) {
        const size_t plane = (size_t)BB * HH * SS * HDIM;
        u16* qkv = (u16*)outv;
        #pragma unroll
        for (int ns = 0; ns < 4; ++ns) {
            int ngl0 = n0 + wn * 64 + ns * 16;
            int which = ngl0 >> 9;
            int nn0 = ngl0 & 511;
            int h = nn0 >> 6;
            int hd = (nn0 & 63) + col;
            const float* bp = (which == 0) ? b0 : (which == 1) ? b1 : b2;
            float bj = bp[nn0 + col];
            // K scale = (1/sqrt(64)) * log2(e): softmax runs in exp2 domain
            float scl = (which == 1) ? 0.18033688011112043f : 1.0f;
            u16* base = qkv + (size_t)which * plane;
            if (which < 2) {
                #pragma unroll
                for (int ms = 0; ms < 4; ++ms) {
                    int m = m0 + wm * 64 + ms * 16 + hi * 4;
                    int b = m >> 12, s = m & 4095;
                    size_t off = ((size_t)(b * HH + h) * SS + s) * HDIM + hd;
                    #pragma unroll
                    for (int r = 0; r < 4; ++r)
                        base[off + (size_t)r * HDIM] = (u16)f2bf((acc[ms][ns][r] + bj) * scl);
                }
            } else {
                #pragma unroll
                for (int ms = 0; ms < 4; ++ms) {
                    int m = m0 + wm * 64 + ms * 16 + hi * 4;
                    int b = m >> 12, s0 = m & 4095;
                    unsigned int lo = f2bf(acc[ms][ns][0] + bj) | (f2bf(acc[ms][ns][1] + bj) << 16);
                    unsigned int hi2 = f2bf(acc[ms][ns][2] + bj) | (f2bf(acc[ms][ns][3] + bj) << 16);
                    *(uint2*)(base + ((size_t)(b * HH + h) * HDIM + hd) * SS + s0) =
                        make_uint2(lo, hi2);
                }
            }
        }
    } else {
        float* out = (float*)outv;
        #pragma unroll
        for (int ns = 0; ns < 4; ++ns) {
            int ngl0 = n0 + wn * 64 + ns * 16;
            float bj = b0[ngl0 + col];
            #pragma unroll
            for (int ms = 0; ms < 4; ++ms) {
                int m = m0 + wm * 64 + ms * 16 + hi * 4;
                #pragma unroll
                for (int r = 0; r < 4; ++r)
                    out[(size_t)(m + r) * 512 + ngl0 + col] = acc[ms][ns][r] + bj;
            }
        }
    }
}

// ---------------- windowed attention: V prefetched to registers ------------
// Block = 64 q rows (4 waves x 16) of one bh; 40KB K->V time-shared LDS,
// 4 blocks/CU. V rounds 0..5 are fetched to REGISTERS concurrently with K's
// staging (drain = max, not sum) and ds_written after the K-dead barrier;
// rounds 6..9 go gload_lds there (drain hides under the writes). P-pack is
// fused into the exp2 loop (defer-norm) to keep peak VGPR < 128.
__global__ __launch_bounds__(256, 4) void attn_mfma(
    const u16* __restrict__ qkv,
    u16* __restrict__ aout)   // (B, S, D) bf16
{
    __shared__ char sbuf[40960];   // K window (320x128B), then V window (64x640B)

    const int tid  = threadIdx.x;
    const int lane = tid & 63;
    const int wave = tid >> 6;
    const int col  = lane & 15;
    const int hi   = lane >> 4;

    const int p = blockIdx.x;
    const int l = (p & 7) * 128 + (p >> 3);
    const int qblk = l & 63;
    const int bh   = l >> 6;

    const int qbase  = qblk * 64 + wave * 16;
    const int wbaseB = qblk * 64 - 128;
    const int wbase  = qbase - 128;

    const size_t plane = (size_t)BB * HH * SS * HDIM;
    const u16* qp = qkv;
    const u16* kp = qp + plane;     // pre-scaled by 0.125*log2(e)
    const u16* vt = qp + 2 * plane; // Vt[bh][hd][s]
    const size_t base = (size_t)bh * SS * HDIM;

    // Q B-fragments (contiguous k map hi*8+e per 32-half)
    const u16* qrow = qp + base + (size_t)(qbase + col) * HDIM;
    Frag qaL, qaH;
    qaL.u = *(const uint4*)(qrow + hi * 8);
    qaH.u = *(const uint4*)(qrow + 32 + hi * 8);

    // ---- stage K: 320 rows x 8 granules, src pre-swizzled g^(r&7)
    #pragma unroll
    for (int rnd = 0; rnd < 10; ++rnd) {
        int f = rnd * 256 + tid;
        int r = f >> 3, g = f & 7;
        int srow = min(max(wbaseB + r, 0), SS - 1);
        int sg = g ^ (r & 7);
        gload16(kp + base + (size_t)srow * HDIM + sg * 8,
                sbuf + (rnd * 256 + wave * 64) * 16);
    }
    // ---- prefetch V rounds 0..5 into registers (in flight alongside K)
    uint4 vr[6];
    #pragma unroll
    for (int rnd = 0; rnd < 6; ++rnd) {
        int f = rnd * 256 + tid;
        int r = f / 40, g = f - r * 40;
        int sv = wbaseB + (g ^ (r & 7)) * 8;
        sv = min(max(sv, 0), SS - 8);               // clamped cols multiply P=0
        vr[rnd] = *(const uint4*)(vt + ((size_t)bh * HDIM + r) * SS + sv);
    }
    __syncthreads();                 // drains K (and V-reg) loads together
    __builtin_amdgcn_sched_barrier(0);

    // ---- QK swapped: sc[t] = C[j][q], j = wbase+16t+4hi+r, q = qbase+col
    const int c7 = col & 7;
    f32x4 sc[17];
    #pragma unroll
    for (int t = 0; t < 17; ++t) {
        int wr = wave * 16 + 16 * t + col;          // wr&7 == col&7
        const char* kb = sbuf + wr * 128;
        Frag kbL, kbH;
        kbL.u = *(const uint4*)(kb + ((hi ^ c7) * 16));
        kbH.u = *(const uint4*)(kb + (((hi | 4) ^ c7) * 16));
        f32x4 z = {0.f, 0.f, 0.f, 0.f};
        __builtin_amdgcn_s_setprio(1);
        f32x4 a = __builtin_amdgcn_mfma_f32_16x16x32_bf16(kbL.v, qaL.v, z, 0, 0, 0);
        sc[t] = __builtin_amdgcn_mfma_f32_16x16x32_bf16(kbH.v, qaH.v, a, 0, 0, 0);
        __builtin_amdgcn_s_setprio(0);
    }

    // ---- mask (scores already in exp2 domain)
    const int iq = qbase + col;
    #pragma unroll
    for (int t = 0; t < 17; ++t) {
        #pragma unroll
        for (int r = 0; r < 4; ++r) {
            int j = wbase + 16 * t + hi * 4 + r;
            bool ok = (j >= 0) && (j < SS) && (j >= iq - WINW) && (j < iq + WINW);
            sc[t][r] = ok ? sc[t][r] : -1e30f;
        }
    }

    // ---- softmax per q-column (exp2 domain), pack fused (sc[t] dies per t)
    float m = sc[0][0];
    #pragma unroll
    for (int t = 0; t < 17; ++t)
        #pragma unroll
        for (int r = 0; r < 4; ++r) m = fmaxf(m, sc[t][r]);
    m = fmaxf(m, __shfl_xor(m, 16));
    m = fmaxf(m, __shfl_xor(m, 32));
    uint2 pk[18];
    float s = 0.f;
    #pragma unroll
    for (int t = 0; t < 17; ++t) {
        float e0 = exp2f(sc[t][0] - m);
        float e1 = exp2f(sc[t][1] - m);
        float e2 = exp2f(sc[t][2] - m);
        float e3 = exp2f(sc[t][3] - m);
        s += (e0 + e1) + (e2 + e3);
        pk[t].x = f2bf(e0) | (f2bf(e1) << 16);
        pk[t].y = f2bf(e2) | (f2bf(e3) << 16);
    }
    pk[17] = make_uint2(0u, 0u);
    s += __shfl_xor(s, 16);
    s += __shfl_xor(s, 32);
    const float inv = 1.f / s;      // normalizer for q = qbase + col

    // ---- route normalizers to the C-layout rows this lane stores:
    // o[n][r] is row q = qbase + 4*hi + r; lane (4*hi+r) holds its inv.
    float invr[4];
    #pragma unroll
    for (int r = 0; r < 4; ++r)
        invr[r] = __shfl(inv, 4 * hi + r);

    // ---- K buffer dead; write prefetched V + stage rounds 6..9
    __syncthreads();
    __builtin_amdgcn_sched_barrier(0);
    #pragma unroll
    for (int rnd = 6; rnd < 10; ++rnd) {
        int f = rnd * 256 + tid;
        int r = f / 40, g = f - r * 40;
        int sv = wbaseB + (g ^ (r & 7)) * 8;
        sv = min(max(sv, 0), SS - 8);
        gload16(vt + ((size_t)bh * HDIM + r) * SS + sv,
                sbuf + (rnd * 256 + wave * 64) * 16);
    }
    #pragma unroll
    for (int rnd = 0; rnd < 6; ++rnd)
        *(uint4*)(sbuf + (size_t)(rnd * 256 + tid) * 16) = vr[rnd];
    __syncthreads();
    __builtin_amdgcn_sched_barrier(0);

    // ---- PV: O[q][d], A = own pk pairs, B = V with matching k-map
    f32x4 o[4];
    #pragma unroll
    for (int n = 0; n < 4; ++n) o[n] = (f32x4){0.f, 0.f, 0.f, 0.f};

    #pragma unroll
    for (int ks = 0; ks < 9; ++ks) {
        Frag pa;
        pa.u = make_uint4(pk[2 * ks].x, pk[2 * ks].y,
                          pk[2 * ks + 1].x, pk[2 * ks + 1].y);
        const int g0 = 2 * wave + 4 * ks + (hi >> 1);   // <= 39
        const int ofs = 8 * (hi & 1);
        #pragma unroll
        for (int n = 0; n < 4; ++n) {
            int row = 16 * n + col;
            const char* rb = sbuf + row * 640;
            Frag vb;
            vb.u.x = ((const unsigned int*)(rb + ((g0 ^ (row & 7)) * 16) + ofs))[0];
            vb.u.y = ((const unsigned int*)(rb + ((g0 ^ (row & 7)) * 16) + ofs))[1];
            vb.u.z = ((const unsigned int*)(rb + (((g0 + 2) ^ (row & 7)) * 16) + ofs))[0];
            vb.u.w = ((const unsigned int*)(rb + (((g0 + 2) ^ (row & 7)) * 16) + ofs))[1];
            __builtin_amdgcn_s_setprio(1);
            o[n] = __builtin_amdgcn_mfma_f32_16x16x32_bf16(pa.v, vb.v, o[n], 0, 0, 0);
            __builtin_amdgcn_s_setprio(0);
        }
    }

    // ---- store: O[q = qbase + hi*4 + r][d = 16n + col], row-matched normalize
    const int b = bh >> 3, h = bh & 7;
    #pragma unroll
    for (int n = 0; n < 4; ++n)
        #pragma unroll
        for (int r = 0; r < 4; ++r) {
            int i = qbase + hi * 4 + r;
            aout[((size_t)b * SS + i) * DD + h * HDIM + 16 * n + col] =
                (u16)f2bf(o[n][r] * invr[r]);
        }
}

extern "C" void kernel_launch(void* const* d_in, const int* in_sizes, int n_in,
                              void* d_out, int out_size, void* d_ws, size_t ws_size,
                              hipStream_t stream) {
    const float* x  = (const float*)d_in[0];
    const float* Wq = (const float*)d_in[1];
    const float* bq = (const float*)d_in[2];
    const float* Wk = (const float*)d_in[3];
    const float* bk = (const float*)d_in[4];
    const float* Wv = (const float*)d_in[5];
    const float* bv = (const float*)d_in[6];
    const float* Wo = (const float*)d_in[7];
    const float* bo = (const float*)d_in[8];
    float* out = (float*)d_out;

    char* ws = (char*)d_ws;
    const size_t plane = (size_t)BB * HH * SS * HDIM;
    u16* qkv = (u16*)ws;
    u16* Xb  = (u16*)(ws + 3 * plane * sizeof(u16));
    u16* aout = Xb;                                     // alias: Xb dead after gemm_qkv
    u16* Wt  = (u16*)(ws + 3 * plane * sizeof(u16) + (size_t)BB * SS * DD * sizeof(u16));
    u16* Wot = Wt + (size_t)3 * 512 * 512;

    prep<<<dim3(2304), dim3(256), 0, stream>>>(x, Xb, Wq, Wk, Wv, Wo, Wt, Wot);
    gemm_bf16<0><<<dim3(64, 12), dim3(256), 0, stream>>>(Xb, Wt, bq, bk, bv, qkv);
    attn_mfma<<<dim3(1024), dim3(256), 0, stream>>>(qkv, aout);
    gemm_bf16<1><<<dim3(64, 4), dim3(256), 0, stream>>>(aout, Wot, bo, bo, bo, out);
}

// Round 17
// 61.302 us; speedup vs baseline: 1.0744x; 1.0744x over previous
//
#include <hip/hip_runtime.h>
#include <hip/hip_bf16.h>

#define BB 2
#define SS 4096
#define DD 512
#define HH 8
#define HDIM 64
#define WINW 128

typedef __attribute__((ext_vector_type(8))) __bf16 bf16x8;
typedef __attribute__((ext_vector_type(4))) float f32x4;
typedef unsigned short u16;

union Frag { bf16x8 v; uint4 u; };

__device__ __forceinline__ unsigned int f2bf(float f) {
    union { __hip_bfloat16 h; unsigned short u; } c;
    c.h = __float2bfloat16(f);
    return (unsigned int)c.u;
}

__device__ __forceinline__ void gload16(const void* g, void* l) {
    __builtin_amdgcn_global_load_lds(
        (const __attribute__((address_space(1))) unsigned int*)g,
        (__attribute__((address_space(3))) unsigned int*)l,
        16, 0, 0);
}

// ---------------- prep: X->bf16  +  W->bf16 transposed (merged) ----------------
__global__ __launch_bounds__(256) void prep(
    const float* __restrict__ X, u16* __restrict__ Xb,
    const float* __restrict__ Wq, const float* __restrict__ Wk,
    const float* __restrict__ Wv, const float* __restrict__ Wo,
    u16* __restrict__ Wt, u16* __restrict__ Wot)
{
    __shared__ float tile[64][65];
    if (blockIdx.x < 2048) {
        int t = blockIdx.x * 256 + threadIdx.x;
        const float4 a = *(const float4*)(X + (size_t)t * 8);
        const float4 b = *(const float4*)(X + (size_t)t * 8 + 4);
        union { u16 s[8]; uint4 u; } p;
        p.s[0] = (u16)f2bf(a.x); p.s[1] = (u16)f2bf(a.y);
        p.s[2] = (u16)f2bf(a.z); p.s[3] = (u16)f2bf(a.w);
        p.s[4] = (u16)f2bf(b.x); p.s[5] = (u16)f2bf(b.y);
        p.s[6] = (u16)f2bf(b.z); p.s[7] = (u16)f2bf(b.w);
        *(uint4*)(Xb + (size_t)t * 8) = p.u;
        return;
    }
    const int bid = blockIdx.x - 2048;          // 0..255
    const int which = bid >> 6;
    const int rem = bid & 63;
    const int k0 = (rem >> 3) * 64, n0 = (rem & 7) * 64;
    const float* W = (which == 0) ? Wq : (which == 1) ? Wk : (which == 2) ? Wv : Wo;
    const int tr = threadIdx.x >> 6, tc = threadIdx.x & 63;
    #pragma unroll
    for (int r = 0; r < 16; ++r)
        tile[tr * 16 + r][tc] = W[(size_t)(k0 + tr * 16 + r) * 512 + n0 + tc];
    __syncthreads();
    u16* dst = (which < 3) ? (Wt + (size_t)which * 512 * 512) : Wot;
    #pragma unroll
    for (int r = 0; r < 16; ++r) {
        int nrow = n0 + tr * 16 + r;
        dst[(size_t)nrow * 512 + k0 + tc] = (u16)f2bf(tile[tc][tr * 16 + r]);
    }
}

// ---------------- bf16 MFMA GEMM (known-good; K-plane pre-scaled 1/8) --------
template<int MODE>
__global__ __launch_bounds__(256) void gemm_bf16(
    const u16* __restrict__ A, const u16* __restrict__ Bt,
    const float* __restrict__ b0, const float* __restrict__ b1,
    const float* __restrict__ b2, void* __restrict__ outv)
{
    __shared__ char lds[16384];
    char* lA = lds;
    char* lB = lds + 8192;
    const int lane = threadIdx.x & 63;
    const int wave = threadIdx.x >> 6;
    const int wm = wave >> 1, wn = wave & 1;
    const int col = lane & 15, hi = lane >> 4;
    const int m0 = blockIdx.x * 128;
    const int n0 = blockIdx.y * 128;

    f32x4 acc[4][4];
    #pragma unroll
    for (int i = 0; i < 4; ++i)
        #pragma unroll
        for (int j = 0; j < 4; ++j) acc[i][j] = (f32x4){0.f, 0.f, 0.f, 0.f};

    char* la0 = lA + (wave * 32) * 64;
    char* la1 = la0 + 16 * 64;
    char* lb0 = lB + (wave * 32) * 64;
    char* lb1 = lb0 + 16 * 64;
    const int sg = (((lane & 3) ^ ((lane >> 2) & 3))) * 16;
    const char* gA = (const char*)(A + (size_t)(m0 + wave * 32 + (lane >> 2)) * 512) + sg;
    const char* gB = (const char*)(Bt + (size_t)(n0 + wave * 32 + (lane >> 2)) * 512) + sg;

    const int x4 = (col & 3);

    for (int kt = 0; kt < 16; ++kt) {
        gload16(gA + kt * 64, la0);
        gload16(gA + 16 * 1024 + kt * 64, la1);
        gload16(gB + kt * 64, lb0);
        gload16(gB + 16 * 1024 + kt * 64, lb1);
        __syncthreads();
        Frag af[4], bf[4];
        #pragma unroll
        for (int ms = 0; ms < 4; ++ms) {
            int R = wm * 64 + ms * 16 + col;
            af[ms].u = *(const uint4*)(lA + R * 64 + ((hi ^ x4) * 16));
        }
        #pragma unroll
        for (int ns = 0; ns < 4; ++ns) {
            int R = wn * 64 + ns * 16 + col;
            bf[ns].u = *(const uint4*)(lB + R * 64 + ((hi ^ x4) * 16));
        }
        __builtin_amdgcn_s_setprio(1);
        #pragma unroll
        for (int ms = 0; ms < 4; ++ms)
            #pragma unroll
            for (int ns = 0; ns < 4; ++ns)
                acc[ms][ns] = __builtin_amdgcn_mfma_f32_16x16x32_bf16(
                    af[ms].v, bf[ns].v, acc[ms][ns], 0, 0, 0);
        __builtin_amdgcn_s_setprio(0);
        __syncthreads();
    }

    if (MODE == 0) {
        const size_t plane = (size_t)BB * HH * SS * HDIM;
        u16* qkv = (u16*)outv;
        #pragma unroll
        for (int ns = 0; ns < 4; ++ns) {
            int ngl0 = n0 + wn * 64 + ns * 16;
            int which = ngl0 >> 9;
            int nn0 = ngl0 & 511;
            int h = nn0 >> 6;
            int hd = (nn0 & 63) + col;
            const float* bp = (which == 0) ? b0 : (which == 1) ? b1 : b2;
            float bj = bp[nn0 + col];
            // fold softmax scale 1/sqrt(64)=2^-3 into K (exact, bit-identical mantissa)
            float scl = (which == 1) ? 0.125f : 1.0f;
            u16* base = qkv + (size_t)which * plane;
            if (which < 2) {
                #pragma unroll
                for (int ms = 0; ms < 4; ++ms) {
                    int m = m0 + wm * 64 + ms * 16 + hi * 4;
                    int b = m >> 12, s = m & 4095;
                    size_t off = ((size_t)(b * HH + h) * SS + s) * HDIM + hd;
                    #pragma unroll
                    for (int r = 0; r < 4; ++r)
                        base[off + (size_t)r * HDIM] = (u16)f2bf((acc[ms][ns][r] + bj) * scl);
                }
            } else {
                #pragma unroll
                for (int ms = 0; ms < 4; ++ms) {
                    int m = m0 + wm * 64 + ms * 16 + hi * 4;
                    int b = m >> 12, s0 = m & 4095;
                    unsigned int lo = f2bf(acc[ms][ns][0] + bj) | (f2bf(acc[ms][ns][1] + bj) << 16);
                    unsigned int hi2 = f2bf(acc[ms][ns][2] + bj) | (f2bf(acc[ms][ns][3] + bj) << 16);
                    *(uint2*)(base + ((size_t)(b * HH + h) * HDIM + hd) * SS + s0) =
                        make_uint2(lo, hi2);
                }
            }
        }
    } else {
        float* out = (float*)outv;
        #pragma unroll
        for (int ns = 0; ns < 4; ++ns) {
            int ngl0 = n0 + wn * 64 + ns * 16;
            float bj = b0[ngl0 + col];
            #pragma unroll
            for (int ms = 0; ms < 4; ++ms) {
                int m = m0 + wm * 64 + ms * 16 + hi * 4;
                #pragma unroll
                for (int r = 0; r < 4; ++r)
                    out[(size_t)(m + r) * 512 + ngl0 + col] = acc[ms][ns][r] + bj;
            }
        }
    }
}

// ---------------- windowed attention (R11 measured-best configuration) ------
// Block = 64 q rows (4 waves x 16) of one bh; 40KB K->V time-shared LDS,
// 4 blocks/CU. Swapped QK (C[j][q]), in-register P, swapped-k-map PV from LDS.
__global__ __launch_bounds__(256, 4) void attn_mfma(
    const u16* __restrict__ qkv,
    u16* __restrict__ aout)   // (B, S, D) bf16
{
    __shared__ char sbuf[40960];   // K window (320x128B), then V window (64x640B)

    const int tid  = threadIdx.x;
    const int lane = tid & 63;
    const int wave = tid >> 6;
    const int col  = lane & 15;
    const int hi   = lane >> 4;

    const int p = blockIdx.x;
    const int l = (p & 7) * 128 + (p >> 3);
    const int qblk = l & 63;
    const int bh   = l >> 6;

    const int qbase  = qblk * 64 + wave * 16;
    const int wbaseB = qblk * 64 - 128;
    const int wbase  = qbase - 128;

    const size_t plane = (size_t)BB * HH * SS * HDIM;
    const u16* qp = qkv;
    const u16* kp = qp + plane;     // pre-scaled by 1/8
    const u16* vt = qp + 2 * plane; // Vt[bh][hd][s]
    const size_t base = (size_t)bh * SS * HDIM;

    // Q B-fragments (contiguous k map hi*8+e per 32-half)
    const u16* qrow = qp + base + (size_t)(qbase + col) * HDIM;
    Frag qaL, qaH;
    qaL.u = *(const uint4*)(qrow + hi * 8);
    qaH.u = *(const uint4*)(qrow + 32 + hi * 8);

    // ---- stage K: 320 rows x 8 granules, src pre-swizzled g^(r&7)
    #pragma unroll
    for (int rnd = 0; rnd < 10; ++rnd) {
        int f = rnd * 256 + tid;
        int r = f >> 3, g = f & 7;
        int srow = min(max(wbaseB + r, 0), SS - 1);
        int sg = g ^ (r & 7);
        gload16(kp + base + (size_t)srow * HDIM + sg * 8,
                sbuf + (rnd * 256 + wave * 64) * 16);
    }
    __syncthreads();

    // ---- QK swapped: sc[t] = C[j][q], j = wbase+16t+4hi+r, q = qbase+col
    const int c7 = col & 7;
    f32x4 sc[17];
    #pragma unroll
    for (int t = 0; t < 17; ++t) {
        int wr = wave * 16 + 16 * t + col;          // wr&7 == col&7
        const char* kb = sbuf + wr * 128;
        Frag kbL, kbH;
        kbL.u = *(const uint4*)(kb + ((hi ^ c7) * 16));
        kbH.u = *(const uint4*)(kb + (((hi | 4) ^ c7) * 16));
        f32x4 z = {0.f, 0.f, 0.f, 0.f};
        __builtin_amdgcn_s_setprio(1);
        f32x4 a = __builtin_amdgcn_mfma_f32_16x16x32_bf16(kbL.v, qaL.v, z, 0, 0, 0);
        sc[t] = __builtin_amdgcn_mfma_f32_16x16x32_bf16(kbH.v, qaH.v, a, 0, 0, 0);
        __builtin_amdgcn_s_setprio(0);
    }

    // ---- mask (scale pre-folded into K)
    const int iq = qbase + col;
    #pragma unroll
    for (int t = 0; t < 17; ++t) {
        #pragma unroll
        for (int r = 0; r < 4; ++r) {
            int j = wbase + 16 * t + hi * 4 + r;
            bool ok = (j >= 0) && (j < SS) && (j >= iq - WINW) && (j < iq + WINW);
            sc[t][r] = ok ? sc[t][r] : -1e30f;
        }
    }

    // ---- softmax per q-column: in-lane 68 + xor16 + xor32
    float m = sc[0][0];
    #pragma unroll
    for (int t = 0; t < 17; ++t)
        #pragma unroll
        for (int r = 0; r < 4; ++r) m = fmaxf(m, sc[t][r]);
    m = fmaxf(m, __shfl_xor(m, 16));
    m = fmaxf(m, __shfl_xor(m, 32));
    float s = 0.f;
    #pragma unroll
    for (int t = 0; t < 17; ++t)
        #pragma unroll
        for (int r = 0; r < 4; ++r) {
            float e = __expf(sc[t][r] - m);
            sc[t][r] = e;
            s += e;
        }
    s += __shfl_xor(s, 16);
    s += __shfl_xor(s, 32);
    const float inv = 1.f / s;

    // ---- pack P to bf16 pairs (in-register)
    uint2 pk[18];
    #pragma unroll
    for (int t = 0; t < 17; ++t) {
        pk[t].x = f2bf(sc[t][0] * inv) | (f2bf(sc[t][1] * inv) << 16);
        pk[t].y = f2bf(sc[t][2] * inv) | (f2bf(sc[t][3] * inv) << 16);
    }
    pk[17] = make_uint2(0u, 0u);

    // ---- all waves done reading K from LDS; restage V into same buffer
    __syncthreads();
    #pragma unroll
    for (int rnd = 0; rnd < 10; ++rnd) {
        int f = rnd * 256 + tid;
        int r = f / 40, g = f - r * 40;
        int sv = wbaseB + (g ^ (r & 7)) * 8;
        sv = min(max(sv, 0), SS - 8);               // clamped cols multiply P=0
        gload16(vt + ((size_t)bh * HDIM + r) * SS + sv,
                sbuf + (rnd * 256 + wave * 64) * 16);
    }
    __syncthreads();

    // ---- PV: O[q][d], A = own pk pairs, B = V with matching k-map
    f32x4 o[4];
    #pragma unroll
    for (int n = 0; n < 4; ++n) o[n] = (f32x4){0.f, 0.f, 0.f, 0.f};

    #pragma unroll
    for (int ks = 0; ks < 9; ++ks) {
        Frag pa;
        pa.u = make_uint4(pk[2 * ks].x, pk[2 * ks].y,
                          pk[2 * ks + 1].x, pk[2 * ks + 1].y);
        const int g0 = 2 * wave + 4 * ks + (hi >> 1);   // <= 39
        const int ofs = 8 * (hi & 1);
        #pragma unroll
        for (int n = 0; n < 4; ++n) {
            int row = 16 * n + col;
            const char* rb = sbuf + row * 640;
            Frag vb;
            vb.u.x = ((const unsigned int*)(rb + ((g0 ^ (row & 7)) * 16) + ofs))[0];
            vb.u.y = ((const unsigned int*)(rb + ((g0 ^ (row & 7)) * 16) + ofs))[1];
            vb.u.z = ((const unsigned int*)(rb + (((g0 + 2) ^ (row & 7)) * 16) + ofs))[0];
            vb.u.w = ((const unsigned int*)(rb + (((g0 + 2) ^ (row & 7)) * 16) + ofs))[1];
            __builtin_amdgcn_s_setprio(1);
            o[n] = __builtin_amdgcn_mfma_f32_16x16x32_bf16(pa.v, vb.v, o[n], 0, 0, 0);
            __builtin_amdgcn_s_setprio(0);
        }
    }

    // ---- store: O[q = qbase + hi*4 + r][d = 16n + col]
    const int b = bh >> 3, h = bh & 7;
    #pragma unroll
    for (int n = 0; n < 4; ++n)
        #pragma unroll
        for (int r = 0; r < 4; ++r) {
            int i = qbase + hi * 4 + r;
            aout[((size_t)b * SS + i) * DD + h * HDIM + 16 * n + col] = (u16)f2bf(o[n][r]);
        }
}

extern "C" void kernel_launch(void* const* d_in, const int* in_sizes, int n_in,
                              void* d_out, int out_size, void* d_ws, size_t ws_size,
                              hipStream_t stream) {
    const float* x  = (const float*)d_in[0];
    const float* Wq = (const float*)d_in[1];
    const float* bq = (const float*)d_in[2];
    const float* Wk = (const float*)d_in[3];
    const float* bk = (const float*)d_in[4];
    const float* Wv = (const float*)d_in[5];
    const float* bv = (const float*)d_in[6];
    const float* Wo = (const float*)d_in[7];
    const float* bo = (const float*)d_in[8];
    float* out = (float*)d_out;

    char* ws = (char*)d_ws;
    const size_t plane = (size_t)BB * HH * SS * HDIM;
    u16* qkv = (u16*)ws;
    u16* Xb  = (u16*)(ws + 3 * plane * sizeof(u16));
    u16* aout = Xb;                                     // alias: Xb dead after gemm_qkv
    u16* Wt  = (u16*)(ws + 3 * plane * sizeof(u16) + (size_t)BB * SS * DD * sizeof(u16));
    u16* Wot = Wt + (size_t)3 * 512 * 512;

    prep<<<dim3(2304), dim3(256), 0, stream>>>(x, Xb, Wq, Wk, Wv, Wo, Wt, Wot);
    gemm_bf16<0><<<dim3(64, 12), dim3(256), 0, stream>>>(Xb, Wt, bq, bk, bv, qkv);
    attn_mfma<<<dim3(1024), dim3(256), 0, stream>>>(qkv, aout);
    gemm_bf16<1><<<dim3(64, 4), dim3(256), 0, stream>>>(aout, Wot, bo, bo, bo, out);
}